// Round 6
// baseline (154.427 us; speedup 1.0000x reference)
//
#include <hip/hip_runtime.h>
#include <hip/hip_fp16.h>
#include <stdint.h>

// out[16384,1024] = fp16(x) @ (fp16(sparsify24(fp16(W))) * scale -> fp16) + bias
#define M_TOT 16384
#define N_TOT 1024
#define K_TOT 1024

typedef _Float16 f16x8 __attribute__((ext_vector_type(8)));
typedef float f32x4 __attribute__((ext_vector_type(4)));
typedef unsigned short ushort4v __attribute__((ext_vector_type(4)));

// async global->LDS DMA, 16B per lane. LDS dest must be wave-uniform base + lane*16.
__device__ inline void gl2lds16(const void* g, void* l) {
    __builtin_amdgcn_global_load_lds(
        (const __attribute__((address_space(1))) void*)(uintptr_t)(g),
        (__attribute__((address_space(3))) void*)(uint32_t)(uintptr_t)(l),
        16, 0, 0);
}

// --- Kernel 1 (fused): blocks [0,256) do weight prep; blocks [256, 256+8192) cast x.
// Both halves are at the HBM streaming floor (~102 MB total traffic).
__global__ void __launch_bounds__(256) prep_and_cast(const float* __restrict__ X,
                                                     const float* __restrict__ W,
                                                     const float* __restrict__ scale_p,
                                                     _Float16* __restrict__ Xh,
                                                     _Float16* __restrict__ wT) {
    const int tid = threadIdx.x;
    if (blockIdx.x < 256) {
        // W[K][N] fp32 -> fp16 -> 2:4 sparsify along N (groups of 4) * scale -> wT[N][K] fp16
        __shared__ _Float16 sT[64 * 68 + 4];   // sT[n][k], stride 68 (pad)
        const float scale = scale_p[0];
        const int k0 = (blockIdx.x & 15) * 64;
        const int n0 = (blockIdx.x >> 4) * 64;
        const int r = tid >> 4;            // 0..15
        const int c4 = (tid & 15) * 4;     // 0..60: one 2:4 group = one float4
#pragma unroll
        for (int p = 0; p < 4; ++p) {
            const int k = p * 16 + r;
            float4 w4 = *(const float4*)&W[(size_t)(k0 + k) * N_TOT + n0 + c4];
            _Float16 h0 = (_Float16)w4.x, h1 = (_Float16)w4.y, h2 = (_Float16)w4.z, h3 = (_Float16)w4.w;
            float a0 = fabsf((float)h0), a1 = fabsf((float)h1), a2 = fabsf((float)h2), a3 = fabsf((float)h3);
            // 2nd-largest of 4; keep a >= s2 (matches ref's a >= sorted[2] tie semantics)
            float lo01 = fminf(a0, a1), hi01 = fmaxf(a0, a1);
            float lo23 = fminf(a2, a3), hi23 = fmaxf(a2, a3);
            float s2 = fmaxf(fminf(hi01, hi23), fmaxf(lo01, lo23));
            sT[(c4 + 0) * 68 + k] = (_Float16)(((a0 >= s2) ? (float)h0 : 0.0f) * scale);
            sT[(c4 + 1) * 68 + k] = (_Float16)(((a1 >= s2) ? (float)h1 : 0.0f) * scale);
            sT[(c4 + 2) * 68 + k] = (_Float16)(((a2 >= s2) ? (float)h2 : 0.0f) * scale);
            sT[(c4 + 3) * 68 + k] = (_Float16)(((a3 >= s2) ? (float)h3 : 0.0f) * scale);
        }
        __syncthreads();
#pragma unroll
        for (int p = 0; p < 4; ++p) {
            const int n = p * 16 + r;
            ushort4v v = *(const ushort4v*)&sT[n * 68 + c4];   // 8B aligned
            *(ushort4v*)&wT[(size_t)(n0 + n) * K_TOT + k0 + c4] = v;
        }
    } else {
        // x fp32 -> fp16 stream (leaves xh hot in L3 for the GEMM)
        size_t i = ((size_t)(blockIdx.x - 256) * 256 + tid) * 8;
        float4 x0 = *(const float4*)&X[i];
        float4 x1 = *(const float4*)&X[i + 4];
        f16x8 h;
        h[0] = (_Float16)x0.x; h[1] = (_Float16)x0.y; h[2] = (_Float16)x0.z; h[3] = (_Float16)x0.w;
        h[4] = (_Float16)x1.x; h[5] = (_Float16)x1.y; h[6] = (_Float16)x1.z; h[7] = (_Float16)x1.w;
        *(f16x8*)&Xh[i] = h;
    }
}

// --- Kernel 2: C = A[M][K] * wT[N][K]^T + bias. 256x128 tile, 512 threads (8 waves),
// BK=64 (two BK=32 sub-tiles), TRUE double-buffer with prefetch distance 1:
//   iter p: __syncthreads (drains stage(p) DMAs — issued one full compute phase ago,
//           and guarantees buf[(p+1)&1]'s prior readers are done)
//         -> issue stage(p+1) DMAs into buf[(p+1)&1]
//         -> ds_read + 64 MFMA/wave on buf[p&1]
// The barrier's forced vmcnt(0) therefore never waits on a cold load: every DMA has
// had ~2600 cyc of MFMA in flight ahead of it (>> 900 cyc HBM latency).
// LDS 96 KB -> 1 block/CU; grid 512 = 2 rounds/CU so round-2 compute overlaps
// round-1 epilogue. r3's version of this structure failed ONLY because of its
// fused fp32 A-cast (2x A bytes, broke L2 sharing, VALU cvt in loop) — A is fp16 here.
// 1D grid swizzled: by = id & 63 -> xcd = id % 8, so the 8 blocks sharing an A-tile
// land on one XCD; per-XCD unique A = 4 MB fp16 -> fits 4 MiB L2.
__global__ void __launch_bounds__(512) gemm_bt(const _Float16* __restrict__ A,
                                               const _Float16* __restrict__ Bt,
                                               const float* __restrict__ bias,
                                               float* __restrict__ C) {
    __shared__ _Float16 sA[2][2][256 * 32];   // [buf][sub-tile s][row][k']
    __shared__ _Float16 sB[2][2][128 * 32];
    const int tid = threadIdx.x;
    const int id = blockIdx.x;
    const int by = id & 63;             // M tile: 0..63 (fastest -> by%8 selects XCD)
    const int bx = id >> 6;             // N tile: 0..7
    const int wave = tid >> 6;          // 0..7
    const int lane = tid & 63;
    const int wm = wave >> 1;           // 0..3 -> M sub-block (64 rows)
    const int wn = wave & 1;            // 0..1 -> N sub-block (64 cols)
    const int quad = lane >> 4;
    const int l16 = lane & 15;

    const int srow = tid >> 2;          // 0..127
    const int scol = (tid & 3) * 8;     // 0,8,16,24

    const _Float16* gA = A + ((size_t)(by * 256 + srow)) * K_TOT + scol;
    const _Float16* gB = Bt + ((size_t)(bx * 128 + srow)) * K_TOT + scol;
    const int soff = srow * 32 + scol;  // byte offset == tid*16 (lane-contiguous, DMA-legal)

    f32x4 acc[4][4];
#pragma unroll
    for (int i = 0; i < 4; ++i)
#pragma unroll
        for (int j = 0; j < 4; ++j)
            acc[i][j] = (f32x4){0.f, 0.f, 0.f, 0.f};

    // stage(phase p) into buf b: A 256x64 (2 sweeps x 2 sub-tiles) + B 128x64
#define STAGE(p, b)                                                              \
    do {                                                                         \
        const int kk = (p) * 64;                                                 \
        gl2lds16(gA + kk,                            &sA[b][0][soff]);           \
        gl2lds16(gA + kk + (size_t)128 * K_TOT,      &sA[b][0][soff + 128 * 32]);\
        gl2lds16(gA + kk + 32,                       &sA[b][1][soff]);           \
        gl2lds16(gA + kk + 32 + (size_t)128 * K_TOT, &sA[b][1][soff + 128 * 32]);\
        gl2lds16(gB + kk,                            &sB[b][0][soff]);           \
        gl2lds16(gB + kk + 32,                       &sB[b][1][soff]);           \
    } while (0)

    STAGE(0, 0);   // prologue: cold-stage phase 0

#pragma unroll 2
    for (int p = 0; p < 16; ++p) {
        const int cur = p & 1;
        const int nxt = cur ^ 1;
        __syncthreads();   // drains stage(p) (in flight ~1 full phase) + frees buf[nxt]

        const int pn = (p + 1 < 16) ? (p + 1) : 0;   // clamp: harmless re-stage
        STAGE(pn, nxt);

#pragma unroll
        for (int s = 0; s < 2; ++s) {
            f16x8 af[4], bf[4];
#pragma unroll
            for (int i = 0; i < 4; ++i) {
                af[i] = *(const f16x8*)&sA[cur][s][(wm * 64 + i * 16 + l16) * 32 + quad * 8];
                bf[i] = *(const f16x8*)&sB[cur][s][(wn * 64 + i * 16 + l16) * 32 + quad * 8];
            }
#pragma unroll
            for (int i = 0; i < 4; ++i)
#pragma unroll
                for (int j = 0; j < 4; ++j)
                    acc[i][j] = __builtin_amdgcn_mfma_f32_16x16x32_f16(af[i], bf[j], acc[i][j], 0, 0, 0);
        }
    }
#undef STAGE

    // epilogue: D row = quad*4 + r, col = l16 per 16x16 tile; bias add, plain stores
#pragma unroll
    for (int j = 0; j < 4; ++j) {
        const int col = bx * 128 + wn * 64 + j * 16 + l16;
        const float bj = bias[col];
#pragma unroll
        for (int i = 0; i < 4; ++i) {
            const int row0 = by * 256 + wm * 64 + i * 16 + quad * 4;
#pragma unroll
            for (int r = 0; r < 4; ++r) {
                C[(size_t)(row0 + r) * N_TOT + col] = acc[i][j][r] + bj;
            }
        }
    }
}

extern "C" void kernel_launch(void* const* d_in, const int* in_sizes, int n_in,
                              void* d_out, int out_size, void* d_ws, size_t ws_size,
                              hipStream_t stream) {
    const float* x      = (const float*)d_in[0];   // [4,4096,1024] fp32
    const float* weight = (const float*)d_in[1];   // [1024,1024] fp32
    const float* bias   = (const float*)d_in[2];   // [1024] fp32
    const float* sscale = (const float*)d_in[3];   // [1] fp32
    float* out = (float*)d_out;

    _Float16* wT = (_Float16*)d_ws;                                    // 2 MiB
    _Float16* xh = (_Float16*)((char*)d_ws + (size_t)2 * 1024 * 1024); // 32 MiB

    prep_and_cast<<<256 + (M_TOT * K_TOT / 8) / 256, 256, 0, stream>>>(x, weight, sscale, xh, wT);
    gemm_bt<<<512, 512, 0, stream>>>(xh, wT, bias, out);
}